// Round 9
// baseline (373.445 us; speedup 1.0000x reference)
//
#include <hip/hip_runtime.h>

typedef unsigned short u16;
typedef short short8 __attribute__((ext_vector_type(8)));
typedef float f32x4 __attribute__((ext_vector_type(4)));

// ---------- helpers ----------
__device__ __forceinline__ u16 f2b(float x){
  union{float f; unsigned u;} v; v.f = x;
  unsigned r = (v.u + 0x7FFFu + ((v.u >> 16) & 1u)) >> 16;
  return (u16)r;
}
__device__ __forceinline__ u16 f2h(float x){
  union{_Float16 h; u16 u;} c; c.h = (_Float16)x; return c.u;
}
__device__ __forceinline__ float b2f(u16 h){
  union{unsigned u; float f;} v; v.u = ((unsigned)h) << 16; return v.f;
}
__device__ __forceinline__ float sigm(float x){ return 1.0f/(1.0f + __expf(-x)); }
__device__ __forceinline__ float tanh_f(float x){ return 1.0f - 2.0f/(1.0f + __expf(2.0f*x)); }

// ---------- prep: xe gather->bf16, Wcomb, bias, Whh k-split f16 repack, W1 repack, hbt pad ----------
__global__ void prep_kernel(const int* __restrict__ x, const float* __restrict__ emb,
   const float* __restrict__ Wih_f, const float* __restrict__ Whh_f,
   const float* __restrict__ bih_f, const float* __restrict__ bhh_f,
   const float* __restrict__ Wih_b, const float* __restrict__ Whh_b,
   const float* __restrict__ bih_b, const float* __restrict__ bhh_b,
   const float* __restrict__ W1,
   u16* __restrict__ xe, u16* __restrict__ wc, float* __restrict__ biasC,
   u16* __restrict__ whh2, u16* __restrict__ w1b, u16* __restrict__ hbt)
{
  int id = blockIdx.x*256 + threadIdx.x;
  const int N0 = 32768*128;   // xe  [p][k]
  const int N1 = 832*128;     // wc  [n][k]
  const int N2 = 800;         // biasC
  const int N3 = 102400;      // whh2 [d][t(400)][g(4)][kq(32)] f16; t=(u,q), k=q*32+kq
  const int N4 = 672*320;     // w1b  (id = k*320+n)
  const int N5 = 32768*24;    // hbt pad cols 200..223
  if (id < N0){
    int p = id >> 7, k = id & 127;
    float v = 0.f;
    if (k < 100) v = emb[x[p]*100 + k];
    xe[id] = f2b(v);
    return;
  }
  id -= N0;
  if (id < N1){
    int n = id >> 7, k = id & 127;
    float v = 0.f;
    if (k < 100){
      if (n < 400) v = Wih_f[n*100+k];
      else if (n < 800) v = Wih_b[(n-400)*100+k];
    }
    wc[id] = f2b(v);
    return;
  }
  id -= N1;
  if (id < N2){
    biasC[id] = (id < 400) ? (bih_f[id]+bhh_f[id]) : (bih_b[id-400]+bhh_b[id-400]);
    return;
  }
  id -= N2;
  if (id < N3){
    int d = id / 51200; int rem = id - d*51200;
    int t = rem >> 7;  int e  = rem & 127;
    int g = e >> 5;    int kq = e & 31;
    int u = t >> 2;    int q  = t & 3;
    int k = q*32 + kq;
    float v = 0.f;
    if (k < 100){
      const float* W = d ? Whh_b : Whh_f;
      v = W[(g*100 + u)*100 + k];
    }
    whh2[id] = f2h(v);
    return;
  }
  id -= N3;
  if (id < N4){
    int k = id / 320; int n = id - k*320;
    int seg = k / 224; int wwk = k - seg*224;
    float v = 0.f;
    if (n < 300 && wwk < 200) v = W1[(seg*200 + wwk)*300 + n];
    w1b[n*672 + k] = f2b(v);
    return;
  }
  id -= N4;
  if (id < N5){
    int p = id / 24; int k = id - p*24;
    hbt[p*224 + 200 + k] = 0;
  }
}

// ---------- GEMM1: inp[d][b][t][u*4+g] = xe @ Wcomb^T + bias, bf16 MFMA ----------
__global__ __launch_bounds__(256) void gemm1_kernel(const u16* __restrict__ xe,
    const u16* __restrict__ wc, const float* __restrict__ biasC, u16* __restrict__ inp)
{
  __shared__ __align__(16) u16 As[64*136];
  __shared__ __align__(16) u16 Bs[64*136];
  const int m0 = blockIdx.x*64, n0 = blockIdx.y*64;
  const int tid = threadIdx.x;
  #pragma unroll
  for (int i=0;i<4;i++){
    int f = i*256 + tid;
    int row = f >> 4, c8 = f & 15;
    *(uint4*)&As[row*136 + c8*8] = *(const uint4*)&xe[(m0+row)*128 + c8*8];
    *(uint4*)&Bs[row*136 + c8*8] = *(const uint4*)&wc[(n0+row)*128 + c8*8];
  }
  __syncthreads();
  const int w = tid >> 6, lane = tid & 63, col = lane & 15, quad = lane >> 4;
  f32x4 acc[4];
  #pragma unroll
  for (int nt=0;nt<4;nt++) acc[nt] = (f32x4){0.f,0.f,0.f,0.f};
  #pragma unroll
  for (int kc=0;kc<4;kc++){
    short8 af = *(const short8*)&As[(w*16+col)*136 + kc*32 + quad*8];
    #pragma unroll
    for (int nt=0;nt<4;nt++){
      short8 bfrag = *(const short8*)&Bs[(nt*16+col)*136 + kc*32 + quad*8];
      acc[nt] = __builtin_amdgcn_mfma_f32_16x16x32_bf16(af, bfrag, acc[nt], 0, 0, 0);
    }
  }
  #pragma unroll
  for (int nt=0;nt<4;nt++){
    int n = n0 + nt*16 + col;
    if (n < 800){
      float bs = biasC[n];
      int dir = (n >= 400) ? 1 : 0;
      int j = n - dir*400;
      int gg = j / 100, uu = j - gg*100;
      int pj = uu*4 + gg;
      #pragma unroll
      for (int r=0;r<4;r++){
        int m = m0 + w*16 + quad*4 + r;
        inp[(dir*32768 + m)*400 + pj] = f2b(acc[nt][r] + bs);
      }
    }
  }
}

// ---------- LSTM recurrence: full-asm, k-split quad + DPP butterfly ----------
// tid -> (u = tid>>2, q = tid&3). Lane owns k-quarter [32q,32q+32) of ALL 4
// gates of unit u: 64 weight dwords v32-v95. Per step: 4 lane-distributed
// ds_read_b128 (each lane reads only its own 64B quarter -- r8's 13 broadcast
// reads + 2 serial ds_swizzle round-trips were the latency floor), 64 v_dot2
// into 4 gate accs, intra-quad butterfly via DPP quad_perm adds (VALU pipe,
// no DS latency), inp preacts as one dwordx2 (4 bf16). Tail activations
// byte-identical to r8 (passed). 96-reg footprint, 2 blocks/CU.
#define DSL(CNT, H0,H1,H2,H3, A0,A1,A2,A3, B0,B1,B2,B3, C0,C1,C2,C3, D0,D1,D2,D3) \
  "s_waitcnt lgkmcnt(" #CNT ")\n\t" \
  "v_dot2_f32_f16 v16, v" #A0 ", v" #H0 ", v16\n\t" \
  "v_dot2_f32_f16 v17, v" #B0 ", v" #H0 ", v17\n\t" \
  "v_dot2_f32_f16 v18, v" #C0 ", v" #H0 ", v18\n\t" \
  "v_dot2_f32_f16 v19, v" #D0 ", v" #H0 ", v19\n\t" \
  "v_dot2_f32_f16 v16, v" #A1 ", v" #H1 ", v16\n\t" \
  "v_dot2_f32_f16 v17, v" #B1 ", v" #H1 ", v17\n\t" \
  "v_dot2_f32_f16 v18, v" #C1 ", v" #H1 ", v18\n\t" \
  "v_dot2_f32_f16 v19, v" #D1 ", v" #H1 ", v19\n\t" \
  "v_dot2_f32_f16 v16, v" #A2 ", v" #H2 ", v16\n\t" \
  "v_dot2_f32_f16 v17, v" #B2 ", v" #H2 ", v17\n\t" \
  "v_dot2_f32_f16 v18, v" #C2 ", v" #H2 ", v18\n\t" \
  "v_dot2_f32_f16 v19, v" #D2 ", v" #H2 ", v19\n\t" \
  "v_dot2_f32_f16 v16, v" #A3 ", v" #H3 ", v16\n\t" \
  "v_dot2_f32_f16 v17, v" #B3 ", v" #H3 ", v17\n\t" \
  "v_dot2_f32_f16 v18, v" #C3 ", v" #H3 ", v18\n\t" \
  "v_dot2_f32_f16 v19, v" #D3 ", v" #H3 ", v19\n\t"

__global__ __launch_bounds__(448) void lstm_kernel(const u16* __restrict__ inp,
    const u16* __restrict__ whh2, u16* __restrict__ hbt)
{
  __shared__ __align__(512) u16 hs2[256];   // [2][128] f16: 256B buffers, XOR 0x100
  const int cid = blockIdx.x;
  const int b = cid & 255, dir = cid >> 8;
  const int tid = threadIdx.x;
  for (int i = tid; i < 128; i += 448) ((float*)hs2)[i] = 0.f;   // pads k>=100 stay 0
  __syncthreads();
  if (tid < 400){
    unsigned long long fe  = __ballot(1);
    unsigned long long g0e = __ballot((tid & 3) == 0);
    unsigned long long g1e = __ballot((tid & 3) == 1);
    const int sw  = tid >> 6;                       // wave id (uniform)
    const int t0  = dir ? 127 : 0;
    const int dIb = dir ? -800 : 800;               // inp byte stride per step
    const int dHb = dir ? -448 : 448;               // hbt byte stride per step
    const int swb = dir*102400;                     // whh2 dir base (bytes)
    const unsigned sio = (unsigned)((dir*32768 + b*128 + t0)*400) * 2u;
    const unsigned sho = (unsigned)((b*128 + t0)*224 + dir*100) * 2u;
    const unsigned sra = (unsigned)(size_t)&hs2[0];
    const unsigned sha = sra + 256u;
    asm volatile(
      // ---- prologue: rebuild tid, per-thread addresses, weight+inp loads ----
      "v_mbcnt_lo_u32_b32 v0, -1, 0\n\t"
      "v_mbcnt_hi_u32_b32 v0, -1, v0\n\t"           // lane
      "v_lshl_add_u32 v0, %[sw], 6, v0\n\t"         // tid
      "v_lshlrev_b32 v1, 8, v0\n\t"                 // tid*256 (weight row bytes)
      "v_add_u32 v1, %[swb], v1\n\t"
      "v_lshrrev_b32 v3, 2, v0\n\t"                 // u
      "v_and_b32 v2, 3, v0\n\t"                     // q
      "v_lshl_add_u32 v23, v2, 6, %[sra]\n\t"       // h read addr = sra + q*64
      "v_lshl_add_u32 v24, v3, 1, %[sha]\n\t"       // h write addr (buf1) + u*2
      "v_lshl_add_u32 v25, v3, 1, %[sho]\n\t"       // hbt addr
      "v_lshl_add_u32 v26, v3, 3, %[sio]\n\t"       // inp addr (+u*8, dwordx2)
      "v_mov_b32 v22, 0\n\t"                        // c
      "s_mov_b32 s20, 128\n\t"
      "global_load_dwordx2 v[20:21], v26, %[ib]\n\t"
      "v_add_u32 v26, %[dis], v26\n\t"
      "global_load_dwordx4 v[32:35], v1, %[wb]\n\t"
      "global_load_dwordx4 v[36:39], v1, %[wb] offset:16\n\t"
      "global_load_dwordx4 v[40:43], v1, %[wb] offset:32\n\t"
      "global_load_dwordx4 v[44:47], v1, %[wb] offset:48\n\t"
      "global_load_dwordx4 v[48:51], v1, %[wb] offset:64\n\t"
      "global_load_dwordx4 v[52:55], v1, %[wb] offset:80\n\t"
      "global_load_dwordx4 v[56:59], v1, %[wb] offset:96\n\t"
      "global_load_dwordx4 v[60:63], v1, %[wb] offset:112\n\t"
      "global_load_dwordx4 v[64:67], v1, %[wb] offset:128\n\t"
      "global_load_dwordx4 v[68:71], v1, %[wb] offset:144\n\t"
      "global_load_dwordx4 v[72:75], v1, %[wb] offset:160\n\t"
      "global_load_dwordx4 v[76:79], v1, %[wb] offset:176\n\t"
      "global_load_dwordx4 v[80:83], v1, %[wb] offset:192\n\t"
      "global_load_dwordx4 v[84:87], v1, %[wb] offset:208\n\t"
      "global_load_dwordx4 v[88:91], v1, %[wb] offset:224\n\t"
      "global_load_dwordx4 v[92:95], v1, %[wb] offset:240\n\t"
      "LSTM_T%=:\n\t"
      // unpack prefetched inp quad (4 bf16 -> 4 f32), reissue next load
      "s_waitcnt vmcnt(0)\n\t"
      "v_lshlrev_b32 v27, 16, v20\n\t"              // pre_i
      "v_and_b32 v28, 0xffff0000, v20\n\t"          // pre_f
      "v_lshlrev_b32 v29, 16, v21\n\t"              // pre_g
      "v_and_b32 v30, 0xffff0000, v21\n\t"          // pre_o
      "global_load_dwordx2 v[20:21], v26, %[ib]\n\t"
      "v_add_u32 v26, %[dis], v26\n\t"
      // h reads: lane's own 64B quarter, 4 x b128
      "ds_read_b128 v[0:3], v23\n\t"
      "ds_read_b128 v[4:7], v23 offset:16\n\t"
      "ds_read_b128 v[8:11], v23 offset:32\n\t"
      "ds_read_b128 v[12:15], v23 offset:48\n\t"
      "v_mov_b32 v16, 0\n\t"
      "v_mov_b32 v17, 0\n\t"
      "v_mov_b32 v18, 0\n\t"
      "v_mov_b32 v19, 0\n\t"
      DSL(3, 0,1,2,3,     32,33,34,35, 48,49,50,51, 64,65,66,67, 80,81,82,83)
      DSL(2, 4,5,6,7,     36,37,38,39, 52,53,54,55, 68,69,70,71, 84,85,86,87)
      DSL(1, 8,9,10,11,   40,41,42,43, 56,57,58,59, 72,73,74,75, 88,89,90,91)
      DSL(0, 12,13,14,15, 44,45,46,47, 60,61,62,63, 76,77,78,79, 92,93,94,95)
      // intra-quad butterfly (xor1 then xor2) on all 4 gate accs via DPP
      "s_nop 1\n\t"
      "v_add_f32_dpp v16, v16, v16 quad_perm:[1,0,3,2] row_mask:0xf bank_mask:0xf\n\t"
      "v_add_f32_dpp v17, v17, v17 quad_perm:[1,0,3,2] row_mask:0xf bank_mask:0xf\n\t"
      "v_add_f32_dpp v18, v18, v18 quad_perm:[1,0,3,2] row_mask:0xf bank_mask:0xf\n\t"
      "v_add_f32_dpp v19, v19, v19 quad_perm:[1,0,3,2] row_mask:0xf bank_mask:0xf\n\t"
      "v_add_f32_dpp v16, v16, v16 quad_perm:[2,3,0,1] row_mask:0xf bank_mask:0xf\n\t"
      "v_add_f32_dpp v17, v17, v17 quad_perm:[2,3,0,1] row_mask:0xf bank_mask:0xf\n\t"
      "v_add_f32_dpp v18, v18, v18 quad_perm:[2,3,0,1] row_mask:0xf bank_mask:0xf\n\t"
      "v_add_f32_dpp v19, v19, v19 quad_perm:[2,3,0,1] row_mask:0xf bank_mask:0xf\n\t"
      "v_add_f32 v16, v16, v27\n\t"                 // iv
      "v_add_f32 v17, v17, v28\n\t"                 // fv
      "v_add_f32 v18, v18, v29\n\t"                 // gv
      "v_add_f32 v19, v19, v30\n\t"                 // ov
      // activations (identical constants/order to r8 -- passed)
      "v_mul_f32 v27, 0xbfb8aa3b, v17\n\t"
      "v_mul_f32 v28, 0xbfb8aa3b, v16\n\t"
      "v_mul_f32 v29, 0x4038aa3b, v18\n\t"
      "v_exp_f32 v27, v27\n\t"
      "v_exp_f32 v28, v28\n\t"
      "v_exp_f32 v29, v29\n\t"
      "v_add_f32 v27, 1.0, v27\n\t"
      "v_add_f32 v28, 1.0, v28\n\t"
      "v_add_f32 v29, 1.0, v29\n\t"
      "v_rcp_f32 v27, v27\n\t"                      // sf
      "v_rcp_f32 v28, v28\n\t"                      // si
      "v_rcp_f32 v29, v29\n\t"
      "v_mov_b32 v30, 1.0\n\t"
      "v_fmac_f32 v30, -2.0, v29\n\t"               // tg
      "v_mul_f32 v28, v28, v30\n\t"                 // si*tg
      "v_fmac_f32 v28, v27, v22\n\t"                // + sf*c
      "v_mov_b32 v22, v28\n\t"                      // c
      "v_mul_f32 v27, 0x4038aa3b, v22\n\t"
      "v_mul_f32 v29, 0xbfb8aa3b, v19\n\t"
      "v_exp_f32 v27, v27\n\t"
      "v_exp_f32 v29, v29\n\t"
      "v_add_f32 v27, 1.0, v27\n\t"
      "v_add_f32 v29, 1.0, v29\n\t"
      "v_rcp_f32 v27, v27\n\t"
      "v_rcp_f32 v29, v29\n\t"                      // so
      "v_mov_b32 v30, 1.0\n\t"
      "v_fmac_f32 v30, -2.0, v27\n\t"               // tc
      "v_mul_f32 v28, v29, v30\n\t"                 // h
      "v_cvt_pk_bf16_f32 v29, v28, v28\n\t"         // bf16 for hbt
      "v_cvt_f16_f32 v27, v28\n\t"                  // f16 for LDS h
      // exec-masked stores: h(f16) -> LDS (q==0), h(bf16) -> hbt (q==1)
      "s_mov_b64 exec, %[g0e]\n\t"
      "ds_write_b16 v24, v27\n\t"
      "s_mov_b64 exec, %[g1e]\n\t"
      "global_store_short v25, v29, %[hb]\n\t"
      "s_mov_b64 exec, %[fe]\n\t"
      "v_add_u32 v25, %[dhs], v25\n\t"
      "v_xor_b32 v23, 0x100, v23\n\t"
      "v_xor_b32 v24, 0x100, v24\n\t"
      "s_waitcnt lgkmcnt(0)\n\t"
      "s_barrier\n\t"
      "s_sub_u32 s20, s20, 1\n\t"
      "s_cmp_lg_u32 s20, 0\n\t"
      "s_cbranch_scc1 LSTM_T%=\n\t"
      :
      : [sw]"s"(sw), [swb]"s"(swb),
        [sio]"s"(sio), [sho]"s"(sho), [sra]"s"(sra), [sha]"s"(sha),
        [wb]"s"(whh2), [ib]"s"(inp), [hb]"s"(hbt),
        [dis]"s"(dIb), [dhs]"s"(dHb),
        [fe]"s"(fe), [g0e]"s"(g0e), [g1e]"s"(g1e)
      : "memory","scc","s20",
        "v0","v1","v2","v3","v4","v5","v6","v7","v8","v9",
        "v10","v11","v12","v13","v14","v15","v16","v17","v18","v19",
        "v20","v21","v22","v23","v24","v25","v26","v27","v28","v29",
        "v30","v31","v32","v33","v34","v35","v36","v37","v38","v39",
        "v40","v41","v42","v43","v44","v45","v46","v47","v48","v49",
        "v50","v51","v52","v53","v54","v55","v56","v57","v58","v59",
        "v60","v61","v62","v63","v64","v65","v66","v67","v68","v69",
        "v70","v71","v72","v73","v74","v75","v76","v77","v78","v79",
        "v80","v81","v82","v83","v84","v85","v86","v87","v88","v89",
        "v90","v91","v92","v93","v94","v95"
    );
  }
}

// ---------- MLP: gathered bf16 MFMA GEMM + tanh + W2 + softmax fused ----------
__global__ __launch_bounds__(512) void mlp_kernel(const u16* __restrict__ hbt,
    const u16* __restrict__ w1b, const int* __restrict__ paths,
    const float* __restrict__ b1, const float* __restrict__ W2,
    const float* __restrict__ b2, float* __restrict__ out)
{
  __shared__ __align__(16) u16 As[128*40];
  __shared__ __align__(16) u16 Bs[320*40];
  const int m0 = blockIdx.x*128;
  const int tid = threadIdx.x;
  const int arow = tid >> 2, ac8 = tid & 3;
  const int am = m0 + arow;
  const int ab = am / 255;
  const int w = tid >> 6, lane = tid & 63, col = lane & 15, quad = lane >> 4;
  f32x4 acc[20];
  #pragma unroll
  for (int nt=0;nt<20;nt++) acc[nt] = (f32x4){0.f,0.f,0.f,0.f};
  for (int kc=0;kc<21;kc++){
    __syncthreads();
    for (int f = tid; f < 1280; f += 512){
      int br = f >> 2, bc = f & 3;
      *(uint4*)&Bs[br*40 + bc*8] = *(const uint4*)&w1b[br*672 + kc*32 + bc*8];
    }
    int seg = (kc >= 14) ? 2 : (kc >= 7 ? 1 : 0);
    int ko = kc - seg*7;
    int it = paths[am*3 + seg];
    uint4 v = make_uint4(0u,0u,0u,0u);
    if (it >= 0){
      int t = it > 127 ? 127 : it;
      v = *(const uint4*)&hbt[(ab*128 + t)*224 + ko*32 + ac8*8];
    }
    *(uint4*)&As[arow*40 + ac8*8] = v;
    __syncthreads();
    short8 af = *(const short8*)&As[(w*16+col)*40 + quad*8];
    #pragma unroll
    for (int nt=0;nt<20;nt++){
      short8 bfrag = *(const short8*)&Bs[(nt*16+col)*40 + quad*8];
      acc[nt] = __builtin_amdgcn_mfma_f32_16x16x32_bf16(af, bfrag, acc[nt], 0, 0, 0);
    }
  }
  float pz[4][3];
  #pragma unroll
  for (int r=0;r<4;r++){ pz[r][0]=0.f; pz[r][1]=0.f; pz[r][2]=0.f; }
  #pragma unroll
  for (int nt=0;nt<20;nt++){
    int n = nt*16 + col;
    if (n < 300){
      float bb = b1[n];
      float w20 = W2[n*3+0], w21 = W2[n*3+1], w22 = W2[n*3+2];
      #pragma unroll
      for (int r=0;r<4;r++){
        float hdn = tanh_f(acc[nt][r] + bb);
        pz[r][0] = fmaf(hdn, w20, pz[r][0]);
        pz[r][1] = fmaf(hdn, w21, pz[r][1]);
        pz[r][2] = fmaf(hdn, w22, pz[r][2]);
      }
    }
  }
  #pragma unroll
  for (int off=1; off<16; off<<=1){
    #pragma unroll
    for (int r=0;r<4;r++){
      pz[r][0] += __shfl_xor(pz[r][0], off, 64);
      pz[r][1] += __shfl_xor(pz[r][1], off, 64);
      pz[r][2] += __shfl_xor(pz[r][2], off, 64);
    }
  }
  float c0 = b2[0], c1 = b2[1], c2 = b2[2];
  #pragma unroll
  for (int r=0;r<4;r++){
    float z0 = pz[r][0]+c0, z1 = pz[r][1]+c1, z2 = pz[r][2]+c2;
    float mx = fmaxf(z0, fmaxf(z1, z2));
    float e0 = __expf(z0-mx), e1 = __expf(z1-mx), e2 = __expf(z2-mx);
    float inv = 1.0f/(e0+e1+e2);
    if (col < 3){
      float pv = (col==0 ? e0 : (col==1 ? e1 : e2)) * inv;
      out[(m0 + w*16 + quad*4 + r)*3 + col] = pv;
    }
  }
}

// ---------- launch ----------
extern "C" void kernel_launch(void* const* d_in, const int* in_sizes, int n_in,
                              void* d_out, int out_size, void* d_ws, size_t ws_size,
                              hipStream_t stream)
{
  const int*   x     = (const int*)  d_in[0];
  const int*   paths = (const int*)  d_in[1];
  const float* emb   = (const float*)d_in[2];
  const float* Wih_f = (const float*)d_in[3];
  const float* Whh_f = (const float*)d_in[4];
  const float* bih_f = (const float*)d_in[5];
  const float* bhh_f = (const float*)d_in[6];
  const float* Wih_b = (const float*)d_in[7];
  const float* Whh_b = (const float*)d_in[8];
  const float* bih_b = (const float*)d_in[9];
  const float* bhh_b = (const float*)d_in[10];
  const float* W1    = (const float*)d_in[11];
  const float* b1    = (const float*)d_in[12];
  const float* W2    = (const float*)d_in[13];
  const float* b2    = (const float*)d_in[14];
  float* out = (float*)d_out;

  char* ws = (char*)d_ws;
  u16*   xe    = (u16*)  (ws + 0);          //  8,388,608 B
  u16*   wc    = (u16*)  (ws + 8388608);    //    212,992 B
  float* biasC = (float*)(ws + 8601600);    //      3,200 B
  u16*   whh2  = (u16*)  (ws + 8604800);    //    204,800 B
  u16*   w1b   = (u16*)  (ws + 8809600);    //    430,080 B
  u16*   inp   = (u16*)  (ws + 9239680);    // 52,428,800 B
  u16*   hbt   = (u16*)  (ws + 61668480);   // 14,680,064 B  (total 76,348,544)

  const int prep_total = 32768*128 + 832*128 + 800 + 102400 + 672*320 + 32768*24;
  prep_kernel<<<(prep_total + 255)/256, 256, 0, stream>>>(
      x, emb, Wih_f, Whh_f, bih_f, bhh_f, Wih_b, Whh_b, bih_b, bhh_b, W1,
      xe, wc, biasC, whh2, w1b, hbt);
  gemm1_kernel<<<dim3(512, 13), 256, 0, stream>>>(xe, wc, biasC, inp);
  lstm_kernel<<<512, 448, 0, stream>>>(inp, whh2, hbt);
  mlp_kernel<<<510, 512, 0, stream>>>(hbt, w1b, paths, b1, W2, b2, out);
}